// Round 12
// baseline (328.521 us; speedup 1.0000x reference)
//
#include <hip/hip_runtime.h>

typedef unsigned short u16;
typedef unsigned int   u32;
typedef __attribute__((ext_vector_type(8))) short bf16x8;
typedef __attribute__((ext_vector_type(4))) float f32x4;

#define SCALE 0.17677669529663687f  // 32^-0.5

__device__ __forceinline__ u16 f2bf(float f){
  u32 x = __float_as_uint(f);
  x += 0x7fffu + ((x >> 16) & 1u);   // RNE
  return (u16)(x >> 16);
}
__device__ __forceinline__ float bf2f(u16 u){
  return __uint_as_float(((u32)u) << 16);
}

// ---- ws layout (bytes) ----
// 0        : qkvw_bf16   [1536][512]            1,572,864
// 1572864  : projw_bf16  [512][512]               524,288
// 2097152  : biasT bf16  [16][64][16][4] permuted 131,072
// 2228224  : scaleT bf16 (same layout)            131,072
// 2359296  : qk bf16 [16384 bh][2][64][32]      134,217,728
// 136577024: vT bf16 [16384 bh][32][64]          67,108,864
// 203685888: x_bf16 [65536][512] (reused attn_o) 67,108,864

// ---------------- prep: weights->bf16, permuted rel tables (r9-proven) ----------------
__global__ void prep_kernel(const float* __restrict__ qkvw, const float* __restrict__ projw,
                            const float* __restrict__ table, const int* __restrict__ relidx,
                            u16* __restrict__ qkvw_b, u16* __restrict__ projw_b,
                            u16* __restrict__ biasT, u16* __restrict__ scaleT){
  int i = blockIdx.x * 256 + threadIdx.x;
  if (i < 786432) {
    qkvw_b[i] = f2bf(qkvw[i]);
  } else if (i < 1048576) {
    int j = i - 786432; projw_b[j] = f2bf(projw[j]);
  } else if (i < 1114112) {
    int j = i - 1048576; int h = j >> 12, rc = j & 4095;
    int idx = relidx[rc];
    int row = rc >> 6, col = rc & 63;
    int noff = h*4096 + row*64 + (col & 15)*4 + (col >> 4);
    biasT [noff] = f2bf(table[idx*32 + h]);
    scaleT[noff] = f2bf(table[idx*32 + 16 + h]);
  }
}

// ---------------- x (fp32) -> bf16 ----------------
__global__ void xconv_kernel(const float* __restrict__ x, u16* __restrict__ xb){
  size_t i = (size_t)blockIdx.x * 256 + threadIdx.x;
  const float4* xp = (const float4*)x;
  float4 a = xp[2*i], b = xp[2*i+1];
  union { u16 u[8]; uint4 v; } o;
  o.u[0]=f2bf(a.x); o.u[1]=f2bf(a.y); o.u[2]=f2bf(a.z); o.u[3]=f2bf(a.w);
  o.u[4]=f2bf(b.x); o.u[5]=f2bf(b.y); o.u[6]=f2bf(b.z); o.u[7]=f2bf(b.w);
  *(uint4*)(xb + 8*i) = o.v;
}

// ============ GEMM (r4-verified loop): BM=BN=256, BK=32, 2-phase, ring-3 ============
// EPI 0: qkv epilogue -> qk [bh][2][64][32] (q scaled) ; v TRANSPOSED -> vT [bh][32][64]
// EPI 1: proj epilogue (bias, fp32 to [M][512])
template<int EPI>
__global__ __launch_bounds__(512, 2) void gemm_kernel(
    const u16* __restrict__ A, const u16* __restrict__ W,
    const float* __restrict__ bias, void* __restrict__ outp, const int NT)
{
  __shared__ u16 lds[3][16384];   // 3 x 32KB = 96KB
  const int tid = threadIdx.x, lane = tid & 63, wid = tid >> 6;
  const int wave_base = tid & ~63;

  const int cpx = gridDim.x >> 3;   // bijective XCD swizzle (grid % 8 == 0)
  const int bid = (blockIdx.x & 7) * cpx + (blockIdx.x >> 3);
  const int mt = bid / NT, nt = bid % NT;
  const size_t m0 = (size_t)mt * 256;
  const int n0 = nt * 256;
  const int wm = wid >> 2, wn = wid & 3;

  const f32x4 z = {0.f, 0.f, 0.f, 0.f};
  f32x4 acc[8][4];
#pragma unroll
  for (int i = 0; i < 8; i++)
#pragma unroll
    for (int j = 0; j < 4; j++) acc[i][j] = z;

  auto stageA = [&](int ch){
    const int slot = ch % 3;
    const int kb = ch * 32;
#pragma unroll
    for (int c = 0; c < 2; ++c){
      const int t = c*512 + tid;
      const int row = t >> 2, sl = t & 3;
      const int lsl = sl ^ ((row >> 1) & 3);
      const u16* ga = A + (m0 + row)*512 + kb + lsl*8;
      u16* la = &lds[slot][(size_t)(c*512 + wave_base)*8];
      __builtin_amdgcn_global_load_lds((const __attribute__((address_space(1))) u32*)ga,
                                       (__attribute__((address_space(3))) u32*)la, 16, 0, 0);
    }
  };
  auto stageB = [&](int ch){
    const int slot = ch % 3;
    const int kb = ch * 32;
#pragma unroll
    for (int c = 0; c < 2; ++c){
      const int t = c*512 + tid;
      const int col = t >> 2, sl = t & 3;
      const int lsl = sl ^ ((col >> 1) & 3);
      const u16* gb = W + (size_t)(n0 + col)*512 + kb + lsl*8;
      u16* lb = &lds[slot][8192 + (size_t)(c*512 + wave_base)*8];
      __builtin_amdgcn_global_load_lds((const __attribute__((address_space(1))) u32*)gb,
                                       (__attribute__((address_space(3))) u32*)lb, 16, 0, 0);
    }
  };

  stageA(0); stageB(0);
  stageA(1); stageB(1);
  asm volatile("s_waitcnt vmcnt(4)" ::: "memory");
  __builtin_amdgcn_s_barrier();

  const int lq = lane & 15, lk = lane >> 4;
#pragma unroll
  for (int ch = 0; ch < 16; ++ch){
    const int slot = ch % 3;
    const u16* As = &lds[slot][0];
    const u16* Bs = &lds[slot][8192];
    bf16x8 af[4], bfr[4], af2[4];

#pragma unroll
    for (int i = 0; i < 4; ++i){
      const int row = wm*128 + i*16 + lq;
      af[i]  = *(const bf16x8*)&As[row*32 + (lk ^ ((row >> 1) & 3))*8];
      const int col = wn*64 + i*16 + lq;
      bfr[i] = *(const bf16x8*)&Bs[col*32 + (lk ^ ((col >> 1) & 3))*8];
    }
    if (ch + 2 < 16) stageA(ch + 2);
    __builtin_amdgcn_s_barrier();
    asm volatile("s_waitcnt lgkmcnt(0)" ::: "memory");
    __builtin_amdgcn_sched_barrier(0);
    __builtin_amdgcn_s_setprio(1);
#pragma unroll
    for (int i = 0; i < 4; ++i)
#pragma unroll
      for (int j = 0; j < 4; ++j)
        acc[i][j] = __builtin_amdgcn_mfma_f32_16x16x32_bf16(af[i], bfr[j], acc[i][j], 0, 0, 0);
    __builtin_amdgcn_s_setprio(0);
    __builtin_amdgcn_s_barrier();

#pragma unroll
    for (int i = 0; i < 4; ++i){
      const int row = wm*128 + 64 + i*16 + lq;
      af2[i] = *(const bf16x8*)&As[row*32 + (lk ^ ((row >> 1) & 3))*8];
    }
    if (ch + 2 < 16) stageB(ch + 2);
    __builtin_amdgcn_s_barrier();
    asm volatile("s_waitcnt lgkmcnt(0)" ::: "memory");
    __builtin_amdgcn_sched_barrier(0);
    __builtin_amdgcn_s_setprio(1);
#pragma unroll
    for (int i = 0; i < 4; ++i)
#pragma unroll
      for (int j = 0; j < 4; ++j)
        acc[4+i][j] = __builtin_amdgcn_mfma_f32_16x16x32_bf16(af2[i], bfr[j], acc[4+i][j], 0, 0, 0);
    __builtin_amdgcn_s_setprio(0);
    if (ch < 14)       { asm volatile("s_waitcnt vmcnt(4)" ::: "memory"); }
    else if (ch == 14) { asm volatile("s_waitcnt vmcnt(0)" ::: "memory"); }
    if (ch < 15) __builtin_amdgcn_s_barrier();
  }

  const int lr = (lane >> 4) << 2;
  const int lc = lane & 15;
  if (EPI == 0){
    u16* o  = (u16*)outp;               // qk [bh][2][64][32]
    u16* ov = o + 67108864;             // vT [bh][32][64]
    const int which = n0 >> 9;          // constant per block (256-col tile in 512 third)
    float bv[4], sc; int pb[4];
    sc = (which == 0) ? SCALE : 1.f;
#pragma unroll
    for (int nf = 0; nf < 4; ++nf){
      const int col = n0 + wn*64 + nf*16 + lc;
      bv[nf] = bias[col];
      const int h = (col >> 5) & 15, d = col & 31;
      pb[nf] = (which < 2) ? ((h*2 + which)*2048 + d) : (h*2048 + d*64);
    }
    if (which < 2){
#pragma unroll
      for (int mf = 0; mf < 8; ++mf){
#pragma unroll
        for (int r = 0; r < 4; ++r){
          const int row = (int)m0 + wm*128 + mf*16 + lr + r;
          const size_t base = (size_t)(row >> 6) * 65536 + (row & 63)*32;
#pragma unroll
          for (int nf = 0; nf < 4; ++nf)
            o[base + pb[nf]] = f2bf((acc[mf][nf][r] + bv[nf]) * sc);
        }
      }
    } else {
#pragma unroll
      for (int mf = 0; mf < 8; ++mf){
#pragma unroll
        for (int r = 0; r < 4; ++r){
          const int row = (int)m0 + wm*128 + mf*16 + lr + r;
          const size_t base = (size_t)(row >> 6) * 32768 + (row & 63);
#pragma unroll
          for (int nf = 0; nf < 4; ++nf)
            ov[base + pb[nf]] = f2bf(acc[mf][nf][r] + bv[nf]);
        }
      }
    }
  } else {
    float* o = (float*)outp;
    float bv[4];
#pragma unroll
    for (int nf = 0; nf < 4; ++nf)
      bv[nf] = bias[n0 + wn*64 + nf*16 + lc];
#pragma unroll
    for (int mf = 0; mf < 8; ++mf){
#pragma unroll
      for (int r = 0; r < 4; ++r){
        const size_t row = m0 + wm*128 + mf*16 + lr + r;
#pragma unroll
        for (int nf = 0; nf < 4; ++nf){
          const int col = n0 + wn*64 + nf*16 + lc;
          o[row*512 + col] = acc[mf][nf][r] + bv[nf];
        }
      }
    }
  }
}

// ---------------- attention: 2 heads/block pipelined, GEMM-proven LDS swizzles ----------------
// grid 8192 = 1024 windows x 8 head-pairs. 256 thr / 4 waves; wave owns 16 q-rows.
// qs/ks [64][32] 16B-slot XOR (row>>1)&3 (r4 GEMM pattern, measured 0-conflict).
// Ps [64][64] slot XOR (row&7) (r6 pattern, measured 0-conflict); wave-private rows.
// vts [32][64] slot XOR (d&7): PV B-frag = ONE contiguous ds_read_b128
// (B[k=kv][col=d] = vT[d][kv]) — replaces 32 scalar ds_read_u16 per lane.
__global__ __launch_bounds__(256) void attn_kernel(
    const u16* __restrict__ qk, const u16* __restrict__ vT,
    const u16* __restrict__ biasT, const u16* __restrict__ scaleT,
    u16* __restrict__ attn_out)
{
  __shared__ u16 qs[2][2048];
  __shared__ u16 ks[2][2048];
  __shared__ u16 vts[2][2048];
  __shared__ u16 Ps[4096];      // [64][64], wave-private row bands
  const int tid = threadIdx.x, lane = tid & 63, wid = tid >> 6;
  const int lq = lane & 15, lg = lane >> 4;
  const int row = tid >> 2, sl = tid & 3;        // q/k staging coords
  const int vd = tid >> 3, vsl = tid & 7;        // v staging coords
  const int b  = blockIdx.x >> 3;
  const int h0 = (blockIdx.x & 7) * 2;
  const u16* qkb = qk + (size_t)b * 65536;
  const u16* vb  = vT + (size_t)b * 32768;
  const int wr0 = wid * 16;
  const f32x4 z = {0.f, 0.f, 0.f, 0.f};

  auto compute = [&](int buf, int h){
    const int qrow = wr0 + lq;
    bf16x8 qf = *(const bf16x8*)&qs[buf][qrow*32 + (lg ^ ((qrow >> 1) & 3))*8];
    f32x4 s[4];
#pragma unroll
    for (int ct = 0; ct < 4; ++ct){
      const int krow = ct*16 + lq;
      bf16x8 kf = *(const bf16x8*)&ks[buf][krow*32 + (lg ^ ((krow >> 1) & 3))*8];
      s[ct] = __builtin_amdgcn_mfma_f32_16x16x32_bf16(qf, kf, z, 0, 0, 0);
    }
    const u16* bT = biasT + h*4096;
    const u16* sT = scaleT + h*4096;
#pragma unroll
    for (int r = 0; r < 4; ++r){
      const int rq = wr0 + lg*4 + r;
      const ushort4 b4 = *(const ushort4*)&bT[rq*64 + lq*4];
      const ushort4 s4 = *(const ushort4*)&sT[rq*64 + lq*4];
      float vals[4];
      vals[0] = s[0][r] + bf2f(b4.x);
      vals[1] = s[1][r] + bf2f(b4.y);
      vals[2] = s[2][r] + bf2f(b4.z);
      vals[3] = s[3][r] + bf2f(b4.w);
      float mx = fmaxf(fmaxf(vals[0], vals[1]), fmaxf(vals[2], vals[3]));
      mx = fmaxf(mx, __shfl_xor(mx, 1));
      mx = fmaxf(mx, __shfl_xor(mx, 2));
      mx = fmaxf(mx, __shfl_xor(mx, 4));
      mx = fmaxf(mx, __shfl_xor(mx, 8));
      float sm = 0.f;
#pragma unroll
      for (int j = 0; j < 4; ++j){ vals[j] = __expf(vals[j] - mx); sm += vals[j]; }
      sm += __shfl_xor(sm, 1);
      sm += __shfl_xor(sm, 2);
      sm += __shfl_xor(sm, 4);
      sm += __shfl_xor(sm, 8);
      const float inv = 1.f / sm;
      const u16 sv[4] = {s4.x, s4.y, s4.z, s4.w};
#pragma unroll
      for (int j = 0; j < 4; ++j){
        const int cs = j*2 + (lq >> 3);            // logical 8-u16 slot of col j*16+lq
        Ps[rq*64 + (cs ^ (rq & 7))*8 + (lq & 7)] = f2bf(vals[j] * inv * bf2f(sv[j]));
      }
    }
    asm volatile("s_waitcnt lgkmcnt(0)" ::: "memory");   // own Ps writes done
    __builtin_amdgcn_sched_barrier(0);

    f32x4 o[2] = {z, z};
#pragma unroll
    for (int kc = 0; kc < 2; ++kc){
      const int prow = wr0 + lq;
      bf16x8 pa = *(const bf16x8*)&Ps[prow*64 + ((kc*4 + lg) ^ (prow & 7))*8];
#pragma unroll
      for (int c2 = 0; c2 < 2; ++c2){
        const int d = c2*16 + lq;
        bf16x8 vf = *(const bf16x8*)&vts[buf][d*64 + ((kc*4 + lg) ^ (d & 7))*8];
        o[c2] = __builtin_amdgcn_mfma_f32_16x16x32_bf16(pa, vf, o[c2], 0, 0, 0);
      }
    }
#pragma unroll
    for (int c2 = 0; c2 < 2; ++c2){
#pragma unroll
      for (int r = 0; r < 4; ++r){
        const int n = wr0 + lg*4 + r;
        attn_out[((size_t)b*64 + n)*512 + h*32 + c2*16 + lq] = f2bf(o[c2][r]);
      }
    }
  };

  // head 0: load + stage (swizzled LDS writes)
  uint4 q0 = *(const uint4*)(qkb + h0*4096 + row*32 + sl*8);
  uint4 k0 = *(const uint4*)(qkb + h0*4096 + 2048 + row*32 + sl*8);
  uint4 v0 = *(const uint4*)(vb + h0*2048 + vd*64 + vsl*8);
  *(uint4*)&qs[0][row*32 + (sl ^ ((row >> 1) & 3))*8] = q0;
  *(uint4*)&ks[0][row*32 + (sl ^ ((row >> 1) & 3))*8] = k0;
  *(uint4*)&vts[0][vd*64 + (vsl ^ (vd & 7))*8] = v0;
  // head 1: issue loads early (latency hides under head-0 compute)
  uint4 q1 = *(const uint4*)(qkb + (h0+1)*4096 + row*32 + sl*8);
  uint4 k1 = *(const uint4*)(qkb + (h0+1)*4096 + 2048 + row*32 + sl*8);
  uint4 v1 = *(const uint4*)(vb + (h0+1)*2048 + vd*64 + vsl*8);
  __syncthreads();

  compute(0, h0);

  *(uint4*)&qs[1][row*32 + (sl ^ ((row >> 1) & 3))*8] = q1;
  *(uint4*)&ks[1][row*32 + (sl ^ ((row >> 1) & 3))*8] = k1;
  *(uint4*)&vts[1][vd*64 + (vsl ^ (vd & 7))*8] = v1;
  __syncthreads();

  compute(1, h0 + 1);
}

extern "C" void kernel_launch(void* const* d_in, const int* in_sizes, int n_in,
                              void* d_out, int out_size, void* d_ws, size_t ws_size,
                              hipStream_t stream)
{
  const float* x      = (const float*)d_in[0];
  const float* qkvw   = (const float*)d_in[1];
  const float* qkvb   = (const float*)d_in[2];
  const float* projw  = (const float*)d_in[3];
  const float* projb  = (const float*)d_in[4];
  const float* table  = (const float*)d_in[5];
  const int*   relidx = (const int*)d_in[6];
  char* ws = (char*)d_ws;

  u16* qkvw_b = (u16*)(ws + 0);
  u16* projw_b= (u16*)(ws + 1572864);
  u16* biasT  = (u16*)(ws + 2097152);
  u16* scaleT = (u16*)(ws + 2228224);
  u16* qkbuf  = (u16*)(ws + 2359296);      // qk [16384][2][64][32]; vT at +67108864 u16
  u16* vTbuf  = (u16*)(ws + 136577024);
  u16* xb     = (u16*)(ws + 203685888);    // x_bf16, reused as attn_o
  u16* attn_o = xb;

  if (ws_size < 270794752ull) return;

  prep_kernel<<<dim3(4352), dim3(256), 0, stream>>>(qkvw, projw, table, relidx,
                                                    qkvw_b, projw_b, biasT, scaleT);
  xconv_kernel<<<dim3(16384), dim3(256), 0, stream>>>(x, xb);
  gemm_kernel<0><<<dim3(1536), dim3(512), 0, stream>>>(xb, qkvw_b, qkvb, (void*)qkbuf, 6);
  attn_kernel<<<dim3(8192), dim3(256), 0, stream>>>(qkbuf, vTbuf, biasT, scaleT, attn_o);
  gemm_kernel<1><<<dim3(512), dim3(512), 0, stream>>>(attn_o, projw_b, projb, d_out, 2);
}

// Round 13
// 309.968 us; speedup vs baseline: 1.0599x; 1.0599x over previous
//
#include <hip/hip_runtime.h>

typedef unsigned short u16;
typedef unsigned int   u32;
typedef __attribute__((ext_vector_type(8))) short bf16x8;
typedef __attribute__((ext_vector_type(4))) float f32x4;

#define SCALE 0.17677669529663687f  // 32^-0.5

__device__ __forceinline__ u16 f2bf(float f){
  u32 x = __float_as_uint(f);
  x += 0x7fffu + ((x >> 16) & 1u);   // RNE
  return (u16)(x >> 16);
}
__device__ __forceinline__ float bf2f(u16 u){
  return __uint_as_float(((u32)u) << 16);
}
// pack 8 fp32 -> bf16x8 via v_cvt_pk_bf16_f32 (RNE, dst.lo = src0)
__device__ __forceinline__ bf16x8 cvt8(f32x4 a, f32x4 b){
  union { u32 w[4]; bf16x8 v; } r;
  asm("v_cvt_pk_bf16_f32 %0, %1, %2" : "=v"(r.w[0]) : "v"(a[0]), "v"(a[1]));
  asm("v_cvt_pk_bf16_f32 %0, %1, %2" : "=v"(r.w[1]) : "v"(a[2]), "v"(a[3]));
  asm("v_cvt_pk_bf16_f32 %0, %1, %2" : "=v"(r.w[2]) : "v"(b[0]), "v"(b[1]));
  asm("v_cvt_pk_bf16_f32 %0, %1, %2" : "=v"(r.w[3]) : "v"(b[2]), "v"(b[3]));
  return r.v;
}

// ---- ws layout (bytes) ----
// 0        : qkvw_bf16   [1536][512]            1,572,864
// 1572864  : projw_bf16  [512][512]               524,288
// 2097152  : biasT bf16  [16][64][16][4] permuted 131,072
// 2228224  : scaleT bf16 (same layout)            131,072
// 2359296  : qkv bf16 [65536][1536] coalesced   201,326,592
// 203685888: attn_o bf16 [65536][512]            67,108,864

// ---------------- prep: weights->bf16, permuted rel tables (r9-proven) ----------------
__global__ void prep_kernel(const float* __restrict__ qkvw, const float* __restrict__ projw,
                            const float* __restrict__ table, const int* __restrict__ relidx,
                            u16* __restrict__ qkvw_b, u16* __restrict__ projw_b,
                            u16* __restrict__ biasT, u16* __restrict__ scaleT){
  int i = blockIdx.x * 256 + threadIdx.x;
  if (i < 786432) {
    qkvw_b[i] = f2bf(qkvw[i]);
  } else if (i < 1048576) {
    int j = i - 786432; projw_b[j] = f2bf(projw[j]);
  } else if (i < 1114112) {
    int j = i - 1048576; int h = j >> 12, rc = j & 4095;
    int idx = relidx[rc];
    int row = rc >> 6, col = rc & 63;
    int noff = h*4096 + row*64 + (col & 15)*4 + (col >> 4);
    biasT [noff] = f2bf(table[idx*32 + h]);
    scaleT[noff] = f2bf(table[idx*32 + 16 + h]);
  }
}

// ============ qkv GEMM with fp32-A staged in LDS (fused x conversion) ============
// C[M][1536] = bf16(X[M][512]) @ W_bf16[1536][512]^T. BM=BN=256, BK=32,
// 2-phase, ring-3. A slot fp32 [256][32] (32KB), B slot bf16 [256][32] (16KB);
// ring-3 = 144KB. A-frags: 2x ds_read_b128 fp32, cvt_pk to bf16 in-reg.
// A swizzle: 8 16B-slots/row, phys = logical ^ (row&7) (src-side + read-side);
// bank = 4*phys_slot mod 32 -> 2 lanes/bank (free). B swizzle = r4 pattern.
// vmcnt: 6 calls/chunk, 2 chunks in flight -> counted vmcnt(6); drain at ch=14.
__global__ __launch_bounds__(512, 2) void gemm_qkv_kernel(
    const float* __restrict__ X, const u16* __restrict__ W,
    const float* __restrict__ bias, u16* __restrict__ outp)
{
  __shared__ u16 lds[3][24576];   // 3 x 48KB = 144KB ; A fp32 @0 (16384 u16), B @16384
  const int tid = threadIdx.x, lane = tid & 63, wid = tid >> 6;
  const int wave_base = tid & ~63;

  const int cpx = gridDim.x >> 3;   // bijective XCD swizzle (1536 % 8 == 0)
  const int bid = (blockIdx.x & 7) * cpx + (blockIdx.x >> 3);
  const int mt = bid / 6, nt = bid % 6;
  const size_t m0 = (size_t)mt * 256;
  const int n0 = nt * 256;
  const int wm = wid >> 2, wn = wid & 3;

  const f32x4 z = {0.f, 0.f, 0.f, 0.f};
  f32x4 acc[8][4];
#pragma unroll
  for (int i = 0; i < 8; i++)
#pragma unroll
    for (int j = 0; j < 4; j++) acc[i][j] = z;

  auto stageA = [&](int ch){   // 4 calls: A fp32 [256 rows][32 k] = 32KB
    const int slot = ch % 3;
    const int kb = ch * 32;
#pragma unroll
    for (int c = 0; c < 4; ++c){
      const int t = c*512 + tid;
      const int row = t >> 3, sl = t & 7;
      const float* ga = X + (m0 + row)*512 + kb + ((sl ^ (row & 7)) << 2);
      u16* la = &lds[slot][(size_t)(c*512 + wave_base)*8];
      __builtin_amdgcn_global_load_lds((const __attribute__((address_space(1))) u32*)ga,
                                       (__attribute__((address_space(3))) u32*)la, 16, 0, 0);
    }
  };
  auto stageB = [&](int ch){   // 2 calls: B bf16 [256 cols][32 k] = 16KB
    const int slot = ch % 3;
    const int kb = ch * 32;
#pragma unroll
    for (int c = 0; c < 2; ++c){
      const int t = c*512 + tid;
      const int col = t >> 2, sl = t & 3;
      const int lsl = sl ^ ((col >> 1) & 3);
      const u16* gb = W + (size_t)(n0 + col)*512 + kb + lsl*8;
      u16* lb = &lds[slot][16384 + (size_t)(c*512 + wave_base)*8];
      __builtin_amdgcn_global_load_lds((const __attribute__((address_space(1))) u32*)gb,
                                       (__attribute__((address_space(3))) u32*)lb, 16, 0, 0);
    }
  };

  stageA(0); stageB(0);
  stageA(1); stageB(1);
  asm volatile("s_waitcnt vmcnt(6)" ::: "memory");
  __builtin_amdgcn_s_barrier();

  const int lq = lane & 15, lk = lane >> 4;
#pragma unroll
  for (int ch = 0; ch < 16; ++ch){
    const int slot = ch % 3;
    const float* Af = (const float*)&lds[slot][0];   // [256][32] fp32
    const u16*   Bs = &lds[slot][16384];
    bf16x8 af[4], bfr[4], af2[4];

#pragma unroll
    for (int i = 0; i < 4; ++i){
      const int row = wm*128 + i*16 + lq;
      f32x4 a0 = *(const f32x4*)&Af[row*32 + ((lk*2    ) ^ (row & 7))*4];
      f32x4 a1 = *(const f32x4*)&Af[row*32 + ((lk*2 + 1) ^ (row & 7))*4];
      af[i] = cvt8(a0, a1);
      const int col = wn*64 + i*16 + lq;
      bfr[i] = *(const bf16x8*)&Bs[col*32 + (lk ^ ((col >> 1) & 3))*8];
    }
    if (ch + 2 < 16) stageA(ch + 2);
    __builtin_amdgcn_s_barrier();
    asm volatile("s_waitcnt lgkmcnt(0)" ::: "memory");
    __builtin_amdgcn_sched_barrier(0);
    __builtin_amdgcn_s_setprio(1);
#pragma unroll
    for (int i = 0; i < 4; ++i)
#pragma unroll
      for (int j = 0; j < 4; ++j)
        acc[i][j] = __builtin_amdgcn_mfma_f32_16x16x32_bf16(af[i], bfr[j], acc[i][j], 0, 0, 0);
    __builtin_amdgcn_s_setprio(0);
    __builtin_amdgcn_s_barrier();

#pragma unroll
    for (int i = 0; i < 4; ++i){
      const int row = wm*128 + 64 + i*16 + lq;
      f32x4 a0 = *(const f32x4*)&Af[row*32 + ((lk*2    ) ^ (row & 7))*4];
      f32x4 a1 = *(const f32x4*)&Af[row*32 + ((lk*2 + 1) ^ (row & 7))*4];
      af2[i] = cvt8(a0, a1);
    }
    if (ch + 2 < 16) stageB(ch + 2);
    __builtin_amdgcn_s_barrier();
    asm volatile("s_waitcnt lgkmcnt(0)" ::: "memory");
    __builtin_amdgcn_sched_barrier(0);
    __builtin_amdgcn_s_setprio(1);
#pragma unroll
    for (int i = 0; i < 4; ++i)
#pragma unroll
      for (int j = 0; j < 4; ++j)
        acc[4+i][j] = __builtin_amdgcn_mfma_f32_16x16x32_bf16(af2[i], bfr[j], acc[4+i][j], 0, 0, 0);
    __builtin_amdgcn_s_setprio(0);
    if (ch < 14)       { asm volatile("s_waitcnt vmcnt(6)" ::: "memory"); }
    else if (ch == 14) { asm volatile("s_waitcnt vmcnt(0)" ::: "memory"); }
    if (ch < 15) __builtin_amdgcn_s_barrier();
  }

  // epilogue (r11-proven): [M][1536] bf16, q pre-scaled, nf innermost
  const int lr = (lane >> 4) << 2;
  const int lc = lane & 15;
  u16* o = outp;
  float bv[4], sc[4];
#pragma unroll
  for (int nf = 0; nf < 4; ++nf){
    const int col = n0 + wn*64 + nf*16 + lc;
    bv[nf] = bias[col];
    sc[nf] = (col < 512) ? SCALE : 1.f;
  }
#pragma unroll
  for (int mf = 0; mf < 8; ++mf){
#pragma unroll
    for (int r = 0; r < 4; ++r){
      const size_t row = m0 + wm*128 + mf*16 + lr + r;
#pragma unroll
      for (int nf = 0; nf < 4; ++nf){
        const int col = n0 + wn*64 + nf*16 + lc;
        o[row*1536 + col] = f2bf((acc[mf][nf][r] + bv[nf]) * sc[nf]);
      }
    }
  }
}

// ============ proj GEMM (r11 EPI1, verbatim): BM=BN=256, BK=32, 2-phase ============
__global__ __launch_bounds__(512, 2) void gemm_proj_kernel(
    const u16* __restrict__ A, const u16* __restrict__ W,
    const float* __restrict__ bias, float* __restrict__ outp)
{
  __shared__ u16 lds[3][16384];   // 96KB
  const int tid = threadIdx.x, lane = tid & 63, wid = tid >> 6;
  const int wave_base = tid & ~63;

  const int cpx = gridDim.x >> 3;
  const int bid = (blockIdx.x & 7) * cpx + (blockIdx.x >> 3);
  const int mt = bid >> 1, nt = bid & 1;
  const size_t m0 = (size_t)mt * 256;
  const int n0 = nt * 256;
  const int wm = wid >> 2, wn = wid & 3;

  const f32x4 z = {0.f, 0.f, 0.f, 0.f};
  f32x4 acc[8][4];
#pragma unroll
  for (int i = 0; i < 8; i++)
#pragma unroll
    for (int j = 0; j < 4; j++) acc[i][j] = z;

  auto stageA = [&](int ch){
    const int slot = ch % 3;
    const int kb = ch * 32;
#pragma unroll
    for (int c = 0; c < 2; ++c){
      const int t = c*512 + tid;
      const int row = t >> 2, sl = t & 3;
      const int lsl = sl ^ ((row >> 1) & 3);
      const u16* ga = A + (m0 + row)*512 + kb + lsl*8;
      u16* la = &lds[slot][(size_t)(c*512 + wave_base)*8];
      __builtin_amdgcn_global_load_lds((const __attribute__((address_space(1))) u32*)ga,
                                       (__attribute__((address_space(3))) u32*)la, 16, 0, 0);
    }
  };
  auto stageB = [&](int ch){
    const int slot = ch % 3;
    const int kb = ch * 32;
#pragma unroll
    for (int c = 0; c < 2; ++c){
      const int t = c*512 + tid;
      const int col = t >> 2, sl = t & 3;
      const int lsl = sl ^ ((col >> 1) & 3);
      const u16* gb = W + (size_t)(n0 + col)*512 + kb + lsl*8;
      u16* lb = &lds[slot][8192 + (size_t)(c*512 + wave_base)*8];
      __builtin_amdgcn_global_load_lds((const __attribute__((address_space(1))) u32*)gb,
                                       (__attribute__((address_space(3))) u32*)lb, 16, 0, 0);
    }
  };

  stageA(0); stageB(0);
  stageA(1); stageB(1);
  asm volatile("s_waitcnt vmcnt(4)" ::: "memory");
  __builtin_amdgcn_s_barrier();

  const int lq = lane & 15, lk = lane >> 4;
#pragma unroll
  for (int ch = 0; ch < 16; ++ch){
    const int slot = ch % 3;
    const u16* As = &lds[slot][0];
    const u16* Bs = &lds[slot][8192];
    bf16x8 af[4], bfr[4], af2[4];

#pragma unroll
    for (int i = 0; i < 4; ++i){
      const int row = wm*128 + i*16 + lq;
      af[i]  = *(const bf16x8*)&As[row*32 + (lk ^ ((row >> 1) & 3))*8];
      const int col = wn*64 + i*16 + lq;
      bfr[i] = *(const bf16x8*)&Bs[col*32 + (lk ^ ((col >> 1) & 3))*8];
    }
    if (ch + 2 < 16) stageA(ch + 2);
    __builtin_amdgcn_s_barrier();
    asm volatile("s_waitcnt lgkmcnt(0)" ::: "memory");
    __builtin_amdgcn_sched_barrier(0);
    __builtin_amdgcn_s_setprio(1);
#pragma unroll
    for (int i = 0; i < 4; ++i)
#pragma unroll
      for (int j = 0; j < 4; ++j)
        acc[i][j] = __builtin_amdgcn_mfma_f32_16x16x32_bf16(af[i], bfr[j], acc[i][j], 0, 0, 0);
    __builtin_amdgcn_s_setprio(0);
    __builtin_amdgcn_s_barrier();

#pragma unroll
    for (int i = 0; i < 4; ++i){
      const int row = wm*128 + 64 + i*16 + lq;
      af2[i] = *(const bf16x8*)&As[row*32 + (lk ^ ((row >> 1) & 3))*8];
    }
    if (ch + 2 < 16) stageB(ch + 2);
    __builtin_amdgcn_s_barrier();
    asm volatile("s_waitcnt lgkmcnt(0)" ::: "memory");
    __builtin_amdgcn_sched_barrier(0);
    __builtin_amdgcn_s_setprio(1);
#pragma unroll
    for (int i = 0; i < 4; ++i)
#pragma unroll
      for (int j = 0; j < 4; ++j)
        acc[4+i][j] = __builtin_amdgcn_mfma_f32_16x16x32_bf16(af2[i], bfr[j], acc[4+i][j], 0, 0, 0);
    __builtin_amdgcn_s_setprio(0);
    if (ch < 14)       { asm volatile("s_waitcnt vmcnt(4)" ::: "memory"); }
    else if (ch == 14) { asm volatile("s_waitcnt vmcnt(0)" ::: "memory"); }
    if (ch < 15) __builtin_amdgcn_s_barrier();
  }

  const int lr = (lane >> 4) << 2;
  const int lc = lane & 15;
  float bv[4];
#pragma unroll
  for (int nf = 0; nf < 4; ++nf)
    bv[nf] = bias[n0 + wn*64 + nf*16 + lc];
#pragma unroll
  for (int mf = 0; mf < 8; ++mf){
#pragma unroll
    for (int r = 0; r < 4; ++r){
      const size_t row = m0 + wm*128 + mf*16 + lr + r;
#pragma unroll
      for (int nf = 0; nf < 4; ++nf){
        const int col = n0 + wn*64 + nf*16 + lc;
        outp[row*512 + col] = acc[mf][nf][r] + bv[nf];
      }
    }
  }
}

// ---------------- attention (r11-verbatim): TWO heads per block, pipelined ----------------
__global__ __launch_bounds__(256) void attn_kernel(
    const u16* __restrict__ qkv, const u16* __restrict__ biasT,
    const u16* __restrict__ scaleT, u16* __restrict__ attn_out)
{
  __shared__ u16 qs[2][2560];   // [64][40]
  __shared__ u16 ks[2][2560];
  __shared__ u16 vs[2][2560];
  __shared__ u16 Ps[4608];      // [64][72], wave-private row bands
  const int tid = threadIdx.x, lane = tid & 63, wid = tid >> 6;
  const int lq = lane & 15, lg = lane >> 4;
  const int row = tid >> 2, sg = (tid & 3) * 8;
  const int b  = blockIdx.x >> 3;
  const int h0 = (blockIdx.x & 7) * 2;
  const u16* pbase = qkv + ((size_t)b*64 + row)*1536 + sg;
  const int wr0 = wid * 16;
  const f32x4 z = {0.f, 0.f, 0.f, 0.f};

  auto compute = [&](int buf, int h){
    bf16x8 qf = *(const bf16x8*)&qs[buf][(wr0 + lq)*40 + lg*8];
    f32x4 s[4];
#pragma unroll
    for (int ct = 0; ct < 4; ++ct){
      bf16x8 kf = *(const bf16x8*)&ks[buf][(ct*16 + lq)*40 + lg*8];
      s[ct] = __builtin_amdgcn_mfma_f32_16x16x32_bf16(qf, kf, z, 0, 0, 0);
    }
    const u16* bT = biasT + h*4096;
    const u16* sT = scaleT + h*4096;
#pragma unroll
    for (int r = 0; r < 4; ++r){
      const int rq = wr0 + lg*4 + r;
      const ushort4 b4 = *(const ushort4*)&bT[rq*64 + lq*4];
      const ushort4 s4 = *(const ushort4*)&sT[rq*64 + lq*4];
      float vals[4];
      vals[0] = s[0][r] + bf2f(b4.x);
      vals[1] = s[1][r] + bf2f(b4.y);
      vals[2] = s[2][r] + bf2f(b4.z);
      vals[3] = s[3][r] + bf2f(b4.w);
      float mx = fmaxf(fmaxf(vals[0], vals[1]), fmaxf(vals[2], vals[3]));
      mx = fmaxf(mx, __shfl_xor(mx, 1));
      mx = fmaxf(mx, __shfl_xor(mx, 2));
      mx = fmaxf(mx, __shfl_xor(mx, 4));
      mx = fmaxf(mx, __shfl_xor(mx, 8));
      float sm = 0.f;
#pragma unroll
      for (int j = 0; j < 4; ++j){ vals[j] = __expf(vals[j] - mx); sm += vals[j]; }
      sm += __shfl_xor(sm, 1);
      sm += __shfl_xor(sm, 2);
      sm += __shfl_xor(sm, 4);
      sm += __shfl_xor(sm, 8);
      const float inv = 1.f / sm;
      const u16 sv[4] = {s4.x, s4.y, s4.z, s4.w};
#pragma unroll
      for (int j = 0; j < 4; ++j)
        Ps[rq*72 + j*16 + lq] = f2bf(vals[j] * inv * bf2f(sv[j]));
    }
    asm volatile("s_waitcnt lgkmcnt(0)" ::: "memory");   // own Ps writes done
    __builtin_amdgcn_sched_barrier(0);

    f32x4 o[2] = {z, z};
#pragma unroll
    for (int kc = 0; kc < 2; ++kc){
      bf16x8 pa = *(const bf16x8*)&Ps[(wr0 + lq)*72 + kc*32 + lg*8];
#pragma unroll
      for (int c2 = 0; c2 < 2; ++c2){
        union { u16 u[8]; bf16x8 v; } vf;
#pragma unroll
        for (int e = 0; e < 8; ++e)
          vf.u[e] = vs[buf][(kc*32 + lg*8 + e)*40 + c2*16 + lq];
        o[c2] = __builtin_amdgcn_mfma_f32_16x16x32_bf16(pa, vf.v, o[c2], 0, 0, 0);
      }
    }
#pragma unroll
    for (int c2 = 0; c2 < 2; ++c2){
#pragma unroll
      for (int r = 0; r < 4; ++r){
        const int n = wr0 + lg*4 + r;
        attn_out[((size_t)b*64 + n)*512 + h*32 + c2*16 + lq] = f2bf(o[c2][r]);
      }
    }
  };

  uint4 q0 = *(const uint4*)(pbase + h0*32);
  uint4 k0 = *(const uint4*)(pbase + 512 + h0*32);
  uint4 v0 = *(const uint4*)(pbase + 1024 + h0*32);
  *(uint4*)&qs[0][row*40 + sg] = q0;
  *(uint4*)&ks[0][row*40 + sg] = k0;
  *(uint4*)&vs[0][row*40 + sg] = v0;
  uint4 q1 = *(const uint4*)(pbase + (h0+1)*32);
  uint4 k1 = *(const uint4*)(pbase + 512 + (h0+1)*32);
  uint4 v1 = *(const uint4*)(pbase + 1024 + (h0+1)*32);
  __syncthreads();

  compute(0, h0);

  *(uint4*)&qs[1][row*40 + sg] = q1;
  *(uint4*)&ks[1][row*40 + sg] = k1;
  *(uint4*)&vs[1][row*40 + sg] = v1;
  __syncthreads();

  compute(1, h0 + 1);
}

extern "C" void kernel_launch(void* const* d_in, const int* in_sizes, int n_in,
                              void* d_out, int out_size, void* d_ws, size_t ws_size,
                              hipStream_t stream)
{
  const float* x      = (const float*)d_in[0];
  const float* qkvw   = (const float*)d_in[1];
  const float* qkvb   = (const float*)d_in[2];
  const float* projw  = (const float*)d_in[3];
  const float* projb  = (const float*)d_in[4];
  const float* table  = (const float*)d_in[5];
  const int*   relidx = (const int*)d_in[6];
  char* ws = (char*)d_ws;

  u16* qkvw_b = (u16*)(ws + 0);
  u16* projw_b= (u16*)(ws + 1572864);
  u16* biasT  = (u16*)(ws + 2097152);
  u16* scaleT = (u16*)(ws + 2228224);
  u16* qkvws  = (u16*)(ws + 2359296);      // [65536][1536] bf16
  u16* attn_o = (u16*)(ws + 203685888);    // [65536][512] bf16

  if (ws_size < 270794752ull) return;

  prep_kernel<<<dim3(4352), dim3(256), 0, stream>>>(qkvw, projw, table, relidx,
                                                    qkvw_b, projw_b, biasT, scaleT);
  gemm_qkv_kernel<<<dim3(1536), dim3(512), 0, stream>>>(x, qkvw_b, qkvb, qkvws);
  attn_kernel<<<dim3(8192), dim3(256), 0, stream>>>(qkvws, biasT, scaleT, attn_o);
  gemm_proj_kernel<<<dim3(512), dim3(512), 0, stream>>>(attn_o, projw_b, projb, (float*)d_out);
}

// Round 14
// 281.472 us; speedup vs baseline: 1.1672x; 1.1012x over previous
//
#include <hip/hip_runtime.h>

typedef unsigned short u16;
typedef unsigned int   u32;
typedef __attribute__((ext_vector_type(8))) short bf16x8;
typedef __attribute__((ext_vector_type(4))) float f32x4;

#define SCALE 0.17677669529663687f  // 32^-0.5

__device__ __forceinline__ u16 f2bf(float f){
  u32 x = __float_as_uint(f);
  x += 0x7fffu + ((x >> 16) & 1u);   // RNE
  return (u16)(x >> 16);
}
__device__ __forceinline__ float bf2f(u16 u){
  return __uint_as_float(((u32)u) << 16);
}

// ---- ws layout (bytes) ----
// 0        : qkvw_bf16   [1536][512]            1,572,864
// 1572864  : projw_bf16  [512][512]               524,288
// 2097152  : biasT bf16  [16][64][16][4] permuted 131,072
// 2228224  : scaleT bf16 (same layout)            131,072
// 2359296  : qkv bf16 [65536][1536] coalesced   201,326,592
// 203685888: x_bf16 [65536][512] (reused attn_o) 67,108,864

// ---------------- merged x-conversion + prep (one dispatch) ----------------
// blocks [0,16384): xconv — thread converts 8 fp32 of x to bf16.
// blocks [16384,20736): prep — weights->bf16, permuted rel tables
//   bias/scale layout: [h][row][lq][j]  (j = col>>4, lq = col&15)
__global__ void prep_xconv_kernel(const float* __restrict__ x, u16* __restrict__ xb,
                                  const float* __restrict__ qkvw, const float* __restrict__ projw,
                                  const float* __restrict__ table, const int* __restrict__ relidx,
                                  u16* __restrict__ qkvw_b, u16* __restrict__ projw_b,
                                  u16* __restrict__ biasT, u16* __restrict__ scaleT){
  if (blockIdx.x < 16384){
    size_t i = (size_t)blockIdx.x * 256 + threadIdx.x;
    const float4* xp = (const float4*)x;
    float4 a = xp[2*i], b = xp[2*i+1];
    union { u16 u[8]; uint4 v; } o;
    o.u[0]=f2bf(a.x); o.u[1]=f2bf(a.y); o.u[2]=f2bf(a.z); o.u[3]=f2bf(a.w);
    o.u[4]=f2bf(b.x); o.u[5]=f2bf(b.y); o.u[6]=f2bf(b.z); o.u[7]=f2bf(b.w);
    *(uint4*)(xb + 8*i) = o.v;
  } else {
    int i = (blockIdx.x - 16384) * 256 + threadIdx.x;
    if (i < 786432) {
      qkvw_b[i] = f2bf(qkvw[i]);
    } else if (i < 1048576) {
      int j = i - 786432; projw_b[j] = f2bf(projw[j]);
    } else if (i < 1114112) {
      int j = i - 1048576; int h = j >> 12, rc = j & 4095;
      int idx = relidx[rc];
      int row = rc >> 6, col = rc & 63;
      int noff = h*4096 + row*64 + (col & 15)*4 + (col >> 4);
      biasT [noff] = f2bf(table[idx*32 + h]);
      scaleT[noff] = f2bf(table[idx*32 + 16 + h]);
    }
  }
}

// ============ GEMM (r4-verified, 128.4us): BM=BN=256, BK=32, 2-phase, ring-3 ============
// EPI 0: qkv epilogue (bias, q*=SCALE, bf16 to [M][1536])
// EPI 1: proj epilogue (bias, fp32 to [M][512])
template<int EPI>
__global__ __launch_bounds__(512, 2) void gemm_kernel(
    const u16* __restrict__ A, const u16* __restrict__ W,
    const float* __restrict__ bias, void* __restrict__ outp, const int NT)
{
  __shared__ u16 lds[3][16384];   // 3 x 32KB = 96KB
  const int tid = threadIdx.x, lane = tid & 63, wid = tid >> 6;
  const int wave_base = tid & ~63;

  const int cpx = gridDim.x >> 3;   // bijective XCD swizzle (grid % 8 == 0)
  const int bid = (blockIdx.x & 7) * cpx + (blockIdx.x >> 3);
  const int mt = bid / NT, nt = bid % NT;
  const size_t m0 = (size_t)mt * 256;
  const int n0 = nt * 256;
  const int wm = wid >> 2, wn = wid & 3;

  const f32x4 z = {0.f, 0.f, 0.f, 0.f};
  f32x4 acc[8][4];
#pragma unroll
  for (int i = 0; i < 8; i++)
#pragma unroll
    for (int j = 0; j < 4; j++) acc[i][j] = z;

  auto stageA = [&](int ch){
    const int slot = ch % 3;
    const int kb = ch * 32;
#pragma unroll
    for (int c = 0; c < 2; ++c){
      const int t = c*512 + tid;
      const int row = t >> 2, sl = t & 3;
      const int lsl = sl ^ ((row >> 1) & 3);
      const u16* ga = A + (m0 + row)*512 + kb + lsl*8;
      u16* la = &lds[slot][(size_t)(c*512 + wave_base)*8];
      __builtin_amdgcn_global_load_lds((const __attribute__((address_space(1))) u32*)ga,
                                       (__attribute__((address_space(3))) u32*)la, 16, 0, 0);
    }
  };
  auto stageB = [&](int ch){
    const int slot = ch % 3;
    const int kb = ch * 32;
#pragma unroll
    for (int c = 0; c < 2; ++c){
      const int t = c*512 + tid;
      const int col = t >> 2, sl = t & 3;
      const int lsl = sl ^ ((col >> 1) & 3);
      const u16* gb = W + (size_t)(n0 + col)*512 + kb + lsl*8;
      u16* lb = &lds[slot][8192 + (size_t)(c*512 + wave_base)*8];
      __builtin_amdgcn_global_load_lds((const __attribute__((address_space(1))) u32*)gb,
                                       (__attribute__((address_space(3))) u32*)lb, 16, 0, 0);
    }
  };

  stageA(0); stageB(0);
  stageA(1); stageB(1);
  asm volatile("s_waitcnt vmcnt(4)" ::: "memory");
  __builtin_amdgcn_s_barrier();

  const int lq = lane & 15, lk = lane >> 4;
#pragma unroll
  for (int ch = 0; ch < 16; ++ch){
    const int slot = ch % 3;
    const u16* As = &lds[slot][0];
    const u16* Bs = &lds[slot][8192];
    bf16x8 af[4], bfr[4], af2[4];

#pragma unroll
    for (int i = 0; i < 4; ++i){
      const int row = wm*128 + i*16 + lq;
      af[i]  = *(const bf16x8*)&As[row*32 + (lk ^ ((row >> 1) & 3))*8];
      const int col = wn*64 + i*16 + lq;
      bfr[i] = *(const bf16x8*)&Bs[col*32 + (lk ^ ((col >> 1) & 3))*8];
    }
    if (ch + 2 < 16) stageA(ch + 2);
    __builtin_amdgcn_s_barrier();
    asm volatile("s_waitcnt lgkmcnt(0)" ::: "memory");
    __builtin_amdgcn_sched_barrier(0);
    __builtin_amdgcn_s_setprio(1);
#pragma unroll
    for (int i = 0; i < 4; ++i)
#pragma unroll
      for (int j = 0; j < 4; ++j)
        acc[i][j] = __builtin_amdgcn_mfma_f32_16x16x32_bf16(af[i], bfr[j], acc[i][j], 0, 0, 0);
    __builtin_amdgcn_s_setprio(0);
    __builtin_amdgcn_s_barrier();

#pragma unroll
    for (int i = 0; i < 4; ++i){
      const int row = wm*128 + 64 + i*16 + lq;
      af2[i] = *(const bf16x8*)&As[row*32 + (lk ^ ((row >> 1) & 3))*8];
    }
    if (ch + 2 < 16) stageB(ch + 2);
    __builtin_amdgcn_s_barrier();
    asm volatile("s_waitcnt lgkmcnt(0)" ::: "memory");
    __builtin_amdgcn_sched_barrier(0);
    __builtin_amdgcn_s_setprio(1);
#pragma unroll
    for (int i = 0; i < 4; ++i)
#pragma unroll
      for (int j = 0; j < 4; ++j)
        acc[4+i][j] = __builtin_amdgcn_mfma_f32_16x16x32_bf16(af2[i], bfr[j], acc[4+i][j], 0, 0, 0);
    __builtin_amdgcn_s_setprio(0);
    if (ch < 14)       { asm volatile("s_waitcnt vmcnt(4)" ::: "memory"); }
    else if (ch == 14) { asm volatile("s_waitcnt vmcnt(0)" ::: "memory"); }
    if (ch < 15) __builtin_amdgcn_s_barrier();
  }

  const int lr = (lane >> 4) << 2;
  const int lc = lane & 15;
  if (EPI == 0){
    u16* o = (u16*)outp;
    float bv[4], sc[4];
#pragma unroll
    for (int nf = 0; nf < 4; ++nf){
      const int col = n0 + wn*64 + nf*16 + lc;
      bv[nf] = bias[col];
      sc[nf] = (col < 512) ? SCALE : 1.f;
    }
#pragma unroll
    for (int mf = 0; mf < 8; ++mf){
#pragma unroll
      for (int r = 0; r < 4; ++r){
        const size_t row = m0 + wm*128 + mf*16 + lr + r;
#pragma unroll
        for (int nf = 0; nf < 4; ++nf){
          const int col = n0 + wn*64 + nf*16 + lc;
          o[row*1536 + col] = f2bf((acc[mf][nf][r] + bv[nf]) * sc[nf]);
        }
      }
    }
  } else {
    float* o = (float*)outp;
    float bv[4];
#pragma unroll
    for (int nf = 0; nf < 4; ++nf)
      bv[nf] = bias[n0 + wn*64 + nf*16 + lc];
#pragma unroll
    for (int mf = 0; mf < 8; ++mf){
#pragma unroll
      for (int r = 0; r < 4; ++r){
        const size_t row = m0 + wm*128 + mf*16 + lr + r;
#pragma unroll
        for (int nf = 0; nf < 4; ++nf){
          const int col = n0 + wn*64 + nf*16 + lc;
          o[row*512 + col] = acc[mf][nf][r] + bv[nf];
        }
      }
    }
  }
}

// ---------------- attention (r11-verbatim): TWO heads per block, pipelined ----------------
// grid 8192 = 1024 windows x 8 head-pairs. 256 thr / 4 waves; wave owns 16 q-rows.
// Pipeline (T14): head1's q/k/v issued into REGS before head0 compute; LDS
// write after. Ps rows are wave-private -> lgkmcnt(0) instead of barrier.
__global__ __launch_bounds__(256) void attn_kernel(
    const u16* __restrict__ qkv, const u16* __restrict__ biasT,
    const u16* __restrict__ scaleT, u16* __restrict__ attn_out)
{
  __shared__ u16 qs[2][2560];   // [64][40]
  __shared__ u16 ks[2][2560];
  __shared__ u16 vs[2][2560];
  __shared__ u16 Ps[4608];      // [64][72], wave-private row bands
  const int tid = threadIdx.x, lane = tid & 63, wid = tid >> 6;
  const int lq = lane & 15, lg = lane >> 4;
  const int row = tid >> 2, sg = (tid & 3) * 8;
  const int b  = blockIdx.x >> 3;
  const int h0 = (blockIdx.x & 7) * 2;
  const u16* pbase = qkv + ((size_t)b*64 + row)*1536 + sg;
  const int wr0 = wid * 16;
  const f32x4 z = {0.f, 0.f, 0.f, 0.f};

  auto compute = [&](int buf, int h){
    bf16x8 qf = *(const bf16x8*)&qs[buf][(wr0 + lq)*40 + lg*8];
    f32x4 s[4];
#pragma unroll
    for (int ct = 0; ct < 4; ++ct){
      bf16x8 kf = *(const bf16x8*)&ks[buf][(ct*16 + lq)*40 + lg*8];
      s[ct] = __builtin_amdgcn_mfma_f32_16x16x32_bf16(qf, kf, z, 0, 0, 0);
    }
    const u16* bT = biasT + h*4096;
    const u16* sT = scaleT + h*4096;
#pragma unroll
    for (int r = 0; r < 4; ++r){
      const int rq = wr0 + lg*4 + r;
      const ushort4 b4 = *(const ushort4*)&bT[rq*64 + lq*4];
      const ushort4 s4 = *(const ushort4*)&sT[rq*64 + lq*4];
      float vals[4];
      vals[0] = s[0][r] + bf2f(b4.x);
      vals[1] = s[1][r] + bf2f(b4.y);
      vals[2] = s[2][r] + bf2f(b4.z);
      vals[3] = s[3][r] + bf2f(b4.w);
      float mx = fmaxf(fmaxf(vals[0], vals[1]), fmaxf(vals[2], vals[3]));
      mx = fmaxf(mx, __shfl_xor(mx, 1));
      mx = fmaxf(mx, __shfl_xor(mx, 2));
      mx = fmaxf(mx, __shfl_xor(mx, 4));
      mx = fmaxf(mx, __shfl_xor(mx, 8));
      float sm = 0.f;
#pragma unroll
      for (int j = 0; j < 4; ++j){ vals[j] = __expf(vals[j] - mx); sm += vals[j]; }
      sm += __shfl_xor(sm, 1);
      sm += __shfl_xor(sm, 2);
      sm += __shfl_xor(sm, 4);
      sm += __shfl_xor(sm, 8);
      const float inv = 1.f / sm;
      const u16 sv[4] = {s4.x, s4.y, s4.z, s4.w};
#pragma unroll
      for (int j = 0; j < 4; ++j)
        Ps[rq*72 + j*16 + lq] = f2bf(vals[j] * inv * bf2f(sv[j]));
    }
    asm volatile("s_waitcnt lgkmcnt(0)" ::: "memory");   // own Ps writes done
    __builtin_amdgcn_sched_barrier(0);

    f32x4 o[2] = {z, z};
#pragma unroll
    for (int kc = 0; kc < 2; ++kc){
      bf16x8 pa = *(const bf16x8*)&Ps[(wr0 + lq)*72 + kc*32 + lg*8];
#pragma unroll
      for (int c2 = 0; c2 < 2; ++c2){
        union { u16 u[8]; bf16x8 v; } vf;
#pragma unroll
        for (int e = 0; e < 8; ++e)
          vf.u[e] = vs[buf][(kc*32 + lg*8 + e)*40 + c2*16 + lq];
        o[c2] = __builtin_amdgcn_mfma_f32_16x16x32_bf16(pa, vf.v, o[c2], 0, 0, 0);
      }
    }
#pragma unroll
    for (int c2 = 0; c2 < 2; ++c2){
#pragma unroll
      for (int r = 0; r < 4; ++r){
        const int n = wr0 + lg*4 + r;
        attn_out[((size_t)b*64 + n)*512 + h*32 + c2*16 + lq] = f2bf(o[c2][r]);
      }
    }
  };

  // head 0: load + stage
  uint4 q0 = *(const uint4*)(pbase + h0*32);
  uint4 k0 = *(const uint4*)(pbase + 512 + h0*32);
  uint4 v0 = *(const uint4*)(pbase + 1024 + h0*32);
  *(uint4*)&qs[0][row*40 + sg] = q0;
  *(uint4*)&ks[0][row*40 + sg] = k0;
  *(uint4*)&vs[0][row*40 + sg] = v0;
  // head 1: issue loads early (latency hides under head-0 compute)
  uint4 q1 = *(const uint4*)(pbase + (h0+1)*32);
  uint4 k1 = *(const uint4*)(pbase + 512 + (h0+1)*32);
  uint4 v1 = *(const uint4*)(pbase + 1024 + (h0+1)*32);
  __syncthreads();

  compute(0, h0);

  *(uint4*)&qs[1][row*40 + sg] = q1;
  *(uint4*)&ks[1][row*40 + sg] = k1;
  *(uint4*)&vs[1][row*40 + sg] = v1;
  __syncthreads();

  compute(1, h0 + 1);
}

extern "C" void kernel_launch(void* const* d_in, const int* in_sizes, int n_in,
                              void* d_out, int out_size, void* d_ws, size_t ws_size,
                              hipStream_t stream)
{
  const float* x      = (const float*)d_in[0];
  const float* qkvw   = (const float*)d_in[1];
  const float* qkvb   = (const float*)d_in[2];
  const float* projw  = (const float*)d_in[3];
  const float* projb  = (const float*)d_in[4];
  const float* table  = (const float*)d_in[5];
  const int*   relidx = (const int*)d_in[6];
  char* ws = (char*)d_ws;

  u16* qkvw_b = (u16*)(ws + 0);
  u16* projw_b= (u16*)(ws + 1572864);
  u16* biasT  = (u16*)(ws + 2097152);
  u16* scaleT = (u16*)(ws + 2228224);
  u16* qkvws  = (u16*)(ws + 2359296);      // [65536][1536] bf16
  u16* xb     = (u16*)(ws + 203685888);    // x_bf16, reused as attn_o
  u16* attn_o = xb;

  if (ws_size < 270794752ull) return;

  prep_xconv_kernel<<<dim3(20736), dim3(256), 0, stream>>>(
      x, xb, qkvw, projw, table, relidx, qkvw_b, projw_b, biasT, scaleT);
  gemm_kernel<0><<<dim3(1536), dim3(512), 0, stream>>>(xb, qkvw_b, qkvb, (void*)qkvws, 6);
  attn_kernel<<<dim3(8192), dim3(256), 0, stream>>>(qkvws, biasT, scaleT, attn_o);
  gemm_kernel<1><<<dim3(512), dim3(512), 0, stream>>>(attn_o, projw_b, projb, d_out, 2);
}

// Round 15
// 276.418 us; speedup vs baseline: 1.1885x; 1.0183x over previous
//
#include <hip/hip_runtime.h>

typedef unsigned short u16;
typedef unsigned int   u32;
typedef __attribute__((ext_vector_type(8))) short bf16x8;
typedef __attribute__((ext_vector_type(4))) float f32x4;

#define SCALE 0.17677669529663687f  // 32^-0.5

__device__ __forceinline__ u16 f2bf(float f){
  u32 x = __float_as_uint(f);
  x += 0x7fffu + ((x >> 16) & 1u);   // RNE
  return (u16)(x >> 16);
}
__device__ __forceinline__ float bf2f(u16 u){
  return __uint_as_float(((u32)u) << 16);
}

// ---- ws layout (bytes) ----
// 0        : qkvw_bf16   [1536][512]            1,572,864
// 1572864  : projw_bf16  [512][512]               524,288
// 2097152  : biasT bf16  [16][64][16][4] permuted 131,072
// 2228224  : scaleT bf16 (same layout)            131,072
// 2359296  : qkv bf16 [65536][1536] coalesced   201,326,592
// 203685888: x_bf16 [65536][512] (reused attn_o) 67,108,864

// ---------------- merged x-conversion + prep (one dispatch, r14-proven) ----------------
__global__ void prep_xconv_kernel(const float* __restrict__ x, u16* __restrict__ xb,
                                  const float* __restrict__ qkvw, const float* __restrict__ projw,
                                  const float* __restrict__ table, const int* __restrict__ relidx,
                                  u16* __restrict__ qkvw_b, u16* __restrict__ projw_b,
                                  u16* __restrict__ biasT, u16* __restrict__ scaleT){
  if (blockIdx.x < 16384){
    size_t i = (size_t)blockIdx.x * 256 + threadIdx.x;
    const float4* xp = (const float4*)x;
    float4 a = xp[2*i], b = xp[2*i+1];
    union { u16 u[8]; uint4 v; } o;
    o.u[0]=f2bf(a.x); o.u[1]=f2bf(a.y); o.u[2]=f2bf(a.z); o.u[3]=f2bf(a.w);
    o.u[4]=f2bf(b.x); o.u[5]=f2bf(b.y); o.u[6]=f2bf(b.z); o.u[7]=f2bf(b.w);
    *(uint4*)(xb + 8*i) = o.v;
  } else {
    int i = (blockIdx.x - 16384) * 256 + threadIdx.x;
    if (i < 786432) {
      qkvw_b[i] = f2bf(qkvw[i]);
    } else if (i < 1048576) {
      int j = i - 786432; projw_b[j] = f2bf(projw[j]);
    } else if (i < 1114112) {
      int j = i - 1048576; int h = j >> 12, rc = j & 4095;
      int idx = relidx[rc];
      int row = rc >> 6, col = rc & 63;
      int noff = h*4096 + row*64 + (col & 15)*4 + (col >> 4);
      biasT [noff] = f2bf(table[idx*32 + h]);
      scaleT[noff] = f2bf(table[idx*32 + 16 + h]);
    }
  }
}

// ============ GEMM (r4-verified, 128.4us): BM=BN=256, BK=32, 2-phase, ring-3 ============
// EPI 0: qkv epilogue (bias, q*=SCALE, bf16 to [M][1536])
// EPI 1: proj epilogue (bias, fp32 to [M][512])
template<int EPI>
__global__ __launch_bounds__(512, 2) void gemm_kernel(
    const u16* __restrict__ A, const u16* __restrict__ W,
    const float* __restrict__ bias, void* __restrict__ outp, const int NT)
{
  __shared__ u16 lds[3][16384];   // 3 x 32KB = 96KB
  const int tid = threadIdx.x, lane = tid & 63, wid = tid >> 6;
  const int wave_base = tid & ~63;

  const int cpx = gridDim.x >> 3;   // bijective XCD swizzle (grid % 8 == 0)
  const int bid = (blockIdx.x & 7) * cpx + (blockIdx.x >> 3);
  const int mt = bid / NT, nt = bid % NT;
  const size_t m0 = (size_t)mt * 256;
  const int n0 = nt * 256;
  const int wm = wid >> 2, wn = wid & 3;

  const f32x4 z = {0.f, 0.f, 0.f, 0.f};
  f32x4 acc[8][4];
#pragma unroll
  for (int i = 0; i < 8; i++)
#pragma unroll
    for (int j = 0; j < 4; j++) acc[i][j] = z;

  auto stageA = [&](int ch){
    const int slot = ch % 3;
    const int kb = ch * 32;
#pragma unroll
    for (int c = 0; c < 2; ++c){
      const int t = c*512 + tid;
      const int row = t >> 2, sl = t & 3;
      const int lsl = sl ^ ((row >> 1) & 3);
      const u16* ga = A + (m0 + row)*512 + kb + lsl*8;
      u16* la = &lds[slot][(size_t)(c*512 + wave_base)*8];
      __builtin_amdgcn_global_load_lds((const __attribute__((address_space(1))) u32*)ga,
                                       (__attribute__((address_space(3))) u32*)la, 16, 0, 0);
    }
  };
  auto stageB = [&](int ch){
    const int slot = ch % 3;
    const int kb = ch * 32;
#pragma unroll
    for (int c = 0; c < 2; ++c){
      const int t = c*512 + tid;
      const int col = t >> 2, sl = t & 3;
      const int lsl = sl ^ ((col >> 1) & 3);
      const u16* gb = W + (size_t)(n0 + col)*512 + kb + lsl*8;
      u16* lb = &lds[slot][8192 + (size_t)(c*512 + wave_base)*8];
      __builtin_amdgcn_global_load_lds((const __attribute__((address_space(1))) u32*)gb,
                                       (__attribute__((address_space(3))) u32*)lb, 16, 0, 0);
    }
  };

  stageA(0); stageB(0);
  stageA(1); stageB(1);
  asm volatile("s_waitcnt vmcnt(4)" ::: "memory");
  __builtin_amdgcn_s_barrier();

  const int lq = lane & 15, lk = lane >> 4;
#pragma unroll
  for (int ch = 0; ch < 16; ++ch){
    const int slot = ch % 3;
    const u16* As = &lds[slot][0];
    const u16* Bs = &lds[slot][8192];
    bf16x8 af[4], bfr[4], af2[4];

#pragma unroll
    for (int i = 0; i < 4; ++i){
      const int row = wm*128 + i*16 + lq;
      af[i]  = *(const bf16x8*)&As[row*32 + (lk ^ ((row >> 1) & 3))*8];
      const int col = wn*64 + i*16 + lq;
      bfr[i] = *(const bf16x8*)&Bs[col*32 + (lk ^ ((col >> 1) & 3))*8];
    }
    if (ch + 2 < 16) stageA(ch + 2);
    __builtin_amdgcn_s_barrier();
    asm volatile("s_waitcnt lgkmcnt(0)" ::: "memory");
    __builtin_amdgcn_sched_barrier(0);
    __builtin_amdgcn_s_setprio(1);
#pragma unroll
    for (int i = 0; i < 4; ++i)
#pragma unroll
      for (int j = 0; j < 4; ++j)
        acc[i][j] = __builtin_amdgcn_mfma_f32_16x16x32_bf16(af[i], bfr[j], acc[i][j], 0, 0, 0);
    __builtin_amdgcn_s_setprio(0);
    __builtin_amdgcn_s_barrier();

#pragma unroll
    for (int i = 0; i < 4; ++i){
      const int row = wm*128 + 64 + i*16 + lq;
      af2[i] = *(const bf16x8*)&As[row*32 + (lk ^ ((row >> 1) & 3))*8];
    }
    if (ch + 2 < 16) stageB(ch + 2);
    __builtin_amdgcn_s_barrier();
    asm volatile("s_waitcnt lgkmcnt(0)" ::: "memory");
    __builtin_amdgcn_sched_barrier(0);
    __builtin_amdgcn_s_setprio(1);
#pragma unroll
    for (int i = 0; i < 4; ++i)
#pragma unroll
      for (int j = 0; j < 4; ++j)
        acc[4+i][j] = __builtin_amdgcn_mfma_f32_16x16x32_bf16(af2[i], bfr[j], acc[4+i][j], 0, 0, 0);
    __builtin_amdgcn_s_setprio(0);
    if (ch < 14)       { asm volatile("s_waitcnt vmcnt(4)" ::: "memory"); }
    else if (ch == 14) { asm volatile("s_waitcnt vmcnt(0)" ::: "memory"); }
    if (ch < 15) __builtin_amdgcn_s_barrier();
  }

  const int lr = (lane >> 4) << 2;
  const int lc = lane & 15;
  if (EPI == 0){
    u16* o = (u16*)outp;
    float bv[4], sc[4];
#pragma unroll
    for (int nf = 0; nf < 4; ++nf){
      const int col = n0 + wn*64 + nf*16 + lc;
      bv[nf] = bias[col];
      sc[nf] = (col < 512) ? SCALE : 1.f;
    }
#pragma unroll
    for (int mf = 0; mf < 8; ++mf){
#pragma unroll
      for (int r = 0; r < 4; ++r){
        const size_t row = m0 + wm*128 + mf*16 + lr + r;
#pragma unroll
        for (int nf = 0; nf < 4; ++nf){
          const int col = n0 + wn*64 + nf*16 + lc;
          o[row*1536 + col] = f2bf((acc[mf][nf][r] + bv[nf]) * sc[nf]);
        }
      }
    }
  } else {
    float* o = (float*)outp;
    float bv[4];
#pragma unroll
    for (int nf = 0; nf < 4; ++nf)
      bv[nf] = bias[n0 + wn*64 + nf*16 + lc];
#pragma unroll
    for (int mf = 0; mf < 8; ++mf){
#pragma unroll
      for (int r = 0; r < 4; ++r){
        const size_t row = m0 + wm*128 + mf*16 + lr + r;
#pragma unroll
        for (int nf = 0; nf < 4; ++nf){
          const int col = n0 + wn*64 + nf*16 + lc;
          o[row*512 + col] = acc[mf][nf][r] + bv[nf];
        }
      }
    }
  }
}

// ---------------- attention: TWO heads per block, pipelined; V transposed in LDS ----------------
// grid 8192 = 1024 windows x 8 head-pairs. 256 thr / 4 waves; wave owns 16 q-rows.
// V staged TRANSPOSED: vt[32 d][stride 72][64 kv] via 8 scalar ds_write_u16
// per thread (latency-hidden stage phase). PV B-frag = ONE aligned ds_read_b128
// (vt[d][kc*32+lg*8..+8] == B[k][col]) — replaces 32 scalar ds_read_u16/lane
// whose lg-groups were 4-way bank-conflicted (rows 8 apart @ 80B ≡ 0 mod 128B).
__global__ __launch_bounds__(256) void attn_kernel(
    const u16* __restrict__ qkv, const u16* __restrict__ biasT,
    const u16* __restrict__ scaleT, u16* __restrict__ attn_out)
{
  __shared__ u16 qs[2][2560];   // [64][40]
  __shared__ u16 ks[2][2560];
  __shared__ u16 vt[2][2304];   // [32 d][72] (cols 0..63 = kv)
  __shared__ u16 Ps[4608];      // [64][72], wave-private row bands
  const int tid = threadIdx.x, lane = tid & 63, wid = tid >> 6;
  const int lq = lane & 15, lg = lane >> 4;
  const int row = tid >> 2, sg = (tid & 3) * 8;
  const int b  = blockIdx.x >> 3;
  const int h0 = (blockIdx.x & 7) * 2;
  const u16* pbase = qkv + ((size_t)b*64 + row)*1536 + sg;
  const int wr0 = wid * 16;
  const f32x4 z = {0.f, 0.f, 0.f, 0.f};

  auto writeV = [&](int buf, uint4 v){
    union { u16 u[8]; uint4 w; } c; c.w = v;
#pragma unroll
    for (int e = 0; e < 8; ++e)
      vt[buf][(sg + e)*72 + row] = c.u[e];   // row = kv, sg+e = d
  };

  auto compute = [&](int buf, int h){
    bf16x8 qf = *(const bf16x8*)&qs[buf][(wr0 + lq)*40 + lg*8];
    f32x4 s[4];
#pragma unroll
    for (int ct = 0; ct < 4; ++ct){
      bf16x8 kf = *(const bf16x8*)&ks[buf][(ct*16 + lq)*40 + lg*8];
      s[ct] = __builtin_amdgcn_mfma_f32_16x16x32_bf16(qf, kf, z, 0, 0, 0);
    }
    const u16* bT = biasT + h*4096;
    const u16* sT = scaleT + h*4096;
#pragma unroll
    for (int r = 0; r < 4; ++r){
      const int rq = wr0 + lg*4 + r;
      const ushort4 b4 = *(const ushort4*)&bT[rq*64 + lq*4];
      const ushort4 s4 = *(const ushort4*)&sT[rq*64 + lq*4];
      float vals[4];
      vals[0] = s[0][r] + bf2f(b4.x);
      vals[1] = s[1][r] + bf2f(b4.y);
      vals[2] = s[2][r] + bf2f(b4.z);
      vals[3] = s[3][r] + bf2f(b4.w);
      float mx = fmaxf(fmaxf(vals[0], vals[1]), fmaxf(vals[2], vals[3]));
      mx = fmaxf(mx, __shfl_xor(mx, 1));
      mx = fmaxf(mx, __shfl_xor(mx, 2));
      mx = fmaxf(mx, __shfl_xor(mx, 4));
      mx = fmaxf(mx, __shfl_xor(mx, 8));
      float sm = 0.f;
#pragma unroll
      for (int j = 0; j < 4; ++j){ vals[j] = __expf(vals[j] - mx); sm += vals[j]; }
      sm += __shfl_xor(sm, 1);
      sm += __shfl_xor(sm, 2);
      sm += __shfl_xor(sm, 4);
      sm += __shfl_xor(sm, 8);
      const float inv = 1.f / sm;
      const u16 sv[4] = {s4.x, s4.y, s4.z, s4.w};
#pragma unroll
      for (int j = 0; j < 4; ++j)
        Ps[rq*72 + j*16 + lq] = f2bf(vals[j] * inv * bf2f(sv[j]));
    }
    asm volatile("s_waitcnt lgkmcnt(0)" ::: "memory");   // own Ps writes done
    __builtin_amdgcn_sched_barrier(0);

    f32x4 o[2] = {z, z};
#pragma unroll
    for (int kc = 0; kc < 2; ++kc){
      bf16x8 pa = *(const bf16x8*)&Ps[(wr0 + lq)*72 + kc*32 + lg*8];
#pragma unroll
      for (int c2 = 0; c2 < 2; ++c2){
        bf16x8 vf = *(const bf16x8*)&vt[buf][(c2*16 + lq)*72 + kc*32 + lg*8];
        o[c2] = __builtin_amdgcn_mfma_f32_16x16x32_bf16(pa, vf, o[c2], 0, 0, 0);
      }
    }
#pragma unroll
    for (int c2 = 0; c2 < 2; ++c2){
#pragma unroll
      for (int r = 0; r < 4; ++r){
        const int n = wr0 + lg*4 + r;
        attn_out[((size_t)b*64 + n)*512 + h*32 + c2*16 + lq] = f2bf(o[c2][r]);
      }
    }
  };

  // head 0: load + stage
  uint4 q0 = *(const uint4*)(pbase + h0*32);
  uint4 k0 = *(const uint4*)(pbase + 512 + h0*32);
  uint4 v0 = *(const uint4*)(pbase + 1024 + h0*32);
  *(uint4*)&qs[0][row*40 + sg] = q0;
  *(uint4*)&ks[0][row*40 + sg] = k0;
  writeV(0, v0);
  // head 1: issue loads early (latency hides under head-0 compute)
  uint4 q1 = *(const uint4*)(pbase + (h0+1)*32);
  uint4 k1 = *(const uint4*)(pbase + 512 + (h0+1)*32);
  uint4 v1 = *(const uint4*)(pbase + 1024 + (h0+1)*32);
  __syncthreads();

  compute(0, h0);

  *(uint4*)&qs[1][row*40 + sg] = q1;
  *(uint4*)&ks[1][row*40 + sg] = k1;
  writeV(1, v1);
  __syncthreads();

  compute(1, h0 + 1);
}

extern "C" void kernel_launch(void* const* d_in, const int* in_sizes, int n_in,
                              void* d_out, int out_size, void* d_ws, size_t ws_size,
                              hipStream_t stream)
{
  const float* x      = (const float*)d_in[0];
  const float* qkvw   = (const float*)d_in[1];
  const float* qkvb   = (const float*)d_in[2];
  const float* projw  = (const float*)d_in[3];
  const float* projb  = (const float*)d_in[4];
  const float* table  = (const float*)d_in[5];
  const int*   relidx = (const int*)d_in[6];
  char* ws = (char*)d_ws;

  u16* qkvw_b = (u16*)(ws + 0);
  u16* projw_b= (u16*)(ws + 1572864);
  u16* biasT  = (u16*)(ws + 2097152);
  u16* scaleT = (u16*)(ws + 2228224);
  u16* qkvws  = (u16*)(ws + 2359296);      // [65536][1536] bf16
  u16* xb     = (u16*)(ws + 203685888);    // x_bf16, reused as attn_o
  u16* attn_o = xb;

  if (ws_size < 270794752ull) return;

  prep_xconv_kernel<<<dim3(20736), dim3(256), 0, stream>>>(
      x, xb, qkvw, projw, table, relidx, qkvw_b, projw_b, biasT, scaleT);
  gemm_kernel<0><<<dim3(1536), dim3(512), 0, stream>>>(xb, qkvw_b, qkvb, (void*)qkvws, 6);
  attn_kernel<<<dim3(8192), dim3(256), 0, stream>>>(qkvws, biasT, scaleT, attn_o);
  gemm_kernel<1><<<dim3(512), dim3(512), 0, stream>>>(attn_o, projw_b, projb, d_out, 2);
}